// Round 1
// baseline (1078.504 us; speedup 1.0000x reference)
//
#include <hip/hip_runtime.h>
#include <cstdint>

// SS2D forward, f32 correctness-first baseline.
// B=8 C=192 H=W=48 L=2304 D_EXP=D_INNER=384 K=4 N=16 R=12
//
// Stages:
//  k_inproj  : xz = in_proj_w @ x ; xx_raw=(B,384,L) raw, z1T=(B,L,384) gelu'd
//  k_conv    : depthwise 3x3 + bias + gelu -> xconv (B,384,L hw-order) and
//              xconvT (B,384,L wh-order)
//  k_xdbl    : per (b,k): x_proj_w[k](44x384) @ xs[b,k] -> xdbl (B,K,48,L)
//              rows 0..11 = dt_raw(r), 12..27 = B(n), 28..43 = C(n)
//  k_scan    : selective scan; delta computed per-64-step chunk in LDS from
//              dt_w/dt_b + dtr rows; thread=(d,n), 16-lane shfl reduce;
//              writes ys (B,K,L,384) in scan order, incl. +u*Ds skip
//  k_merge   : cross-merge (index math) + LayerNorm over D + *z1 -> yln (B,L,384)
//  k_outproj : out_proj_w(192x384) @ yln^T -> out (B,192,L)

static constexpr int L = 2304;

__device__ __forceinline__ float gelu_f(float x) {
  return 0.5f * x * (1.0f + erff(x * 0.70710678118654752440f));
}

// ---------------------------------------------------------------- in_proj
__global__ __launch_bounds__(256) void k_inproj(const float* __restrict__ x,
                                                const float* __restrict__ Wp,
                                                float* __restrict__ xx,
                                                float* __restrict__ z1T) {
  const int b = blockIdx.z;
  const int m0 = blockIdx.y * 64;   // output channel tile (0..768)
  const int n0 = blockIdx.x * 64;   // l tile
  const int tid = threadIdx.x;
  const int tx = tid & 15, ty = tid >> 4;
  __shared__ __align__(16) float As[16][64];
  __shared__ __align__(16) float Bs[16][64];
  __shared__ __align__(16) float zt[64][68];
  float acc[4][4] = {};
  const float* xb = x + (size_t)b * 192 * L;
  for (int c0 = 0; c0 < 192; c0 += 16) {
    {
      const int mm = tid & 63, kq = tid >> 6;
      float4 a = *(const float4*)&Wp[(size_t)(m0 + mm) * 192 + c0 + kq * 4];
      As[kq * 4 + 0][mm] = a.x; As[kq * 4 + 1][mm] = a.y;
      As[kq * 4 + 2][mm] = a.z; As[kq * 4 + 3][mm] = a.w;
    }
    {
      const int n4 = (tid & 15) * 4, kk = tid >> 4;
      *(float4*)&Bs[kk][n4] = *(const float4*)&xb[(size_t)(c0 + kk) * L + n0 + n4];
    }
    __syncthreads();
#pragma unroll
    for (int kk = 0; kk < 16; ++kk) {
      float4 a4 = *(const float4*)&As[kk][ty * 4];
      float4 b4 = *(const float4*)&Bs[kk][tx * 4];
      float av[4] = {a4.x, a4.y, a4.z, a4.w};
      float bv[4] = {b4.x, b4.y, b4.z, b4.w};
#pragma unroll
      for (int i = 0; i < 4; ++i)
#pragma unroll
        for (int j = 0; j < 4; ++j) acc[i][j] = fmaf(av[i], bv[j], acc[i][j]);
    }
    __syncthreads();
  }
  if (m0 < 384) {
#pragma unroll
    for (int i = 0; i < 4; ++i) {
      int m = m0 + ty * 4 + i;
      float4 v = make_float4(acc[i][0], acc[i][1], acc[i][2], acc[i][3]);
      *(float4*)&xx[((size_t)b * 384 + m) * L + n0 + tx * 4] = v;
    }
  } else {
#pragma unroll
    for (int i = 0; i < 4; ++i)
#pragma unroll
      for (int j = 0; j < 4; ++j) zt[tx * 4 + j][ty * 4 + i] = gelu_f(acc[i][j]);
    __syncthreads();
    const int r = tid >> 2, cb = (tid & 3) * 16;
#pragma unroll
    for (int q = 0; q < 4; ++q) {
      int c = cb + q * 4;
      float4 v = make_float4(zt[r][c], zt[r][c + 1], zt[r][c + 2], zt[r][c + 3]);
      *(float4*)&z1T[((size_t)b * L + n0 + r) * 384 + (m0 - 384) + c] = v;
    }
  }
}

// ---------------------------------------------------------------- dw conv
__global__ __launch_bounds__(256) void k_conv(const float* __restrict__ xx,
                                              const float* __restrict__ conv_w,
                                              const float* __restrict__ conv_b,
                                              float* __restrict__ xc,
                                              float* __restrict__ xcT) {
  const int bid = blockIdx.x;
  const int d = bid % 384, b = bid / 384;
  const int tid = threadIdx.x;
  __shared__ float ls[48 * 49];
  __shared__ float xg[48 * 49];
  const float* src = xx + ((size_t)b * 384 + d) * L;
  for (int i = tid; i < L; i += 256) ls[(i / 48) * 49 + (i % 48)] = src[i];
  float cw[9];
  const float* cwp = conv_w + (size_t)d * 9;
#pragma unroll
  for (int r = 0; r < 9; ++r) cw[r] = cwp[r];
  const float cb = conv_b[d];
  __syncthreads();
  float* dst = xc + ((size_t)b * 384 + d) * L;
  for (int p = tid; p < L; p += 256) {
    int h = p / 48, w = p % 48;
    float acc = cb;
#pragma unroll
    for (int dy = -1; dy <= 1; ++dy) {
      int hh = h + dy;
      if (hh < 0 || hh >= 48) continue;
#pragma unroll
      for (int dx = -1; dx <= 1; ++dx) {
        int ww = w + dx;
        if (ww < 0 || ww >= 48) continue;
        acc = fmaf(ls[hh * 49 + ww], cw[(dy + 1) * 3 + (dx + 1)], acc);
      }
    }
    float g = gelu_f(acc);
    dst[p] = g;
    xg[h * 49 + w] = g;
  }
  __syncthreads();
  float* dstT = xcT + ((size_t)b * 384 + d) * L;
  for (int j = tid; j < L; j += 256) {
    int h = j % 48, w = j / 48;
    dstT[j] = xg[h * 49 + w];
  }
}

// ---------------------------------------------------------------- x_proj
__global__ __launch_bounds__(256) void k_xdbl(const float* __restrict__ xc,
                                              const float* __restrict__ xcT,
                                              const float* __restrict__ xpw,
                                              float* __restrict__ xdbl) {
  const int n0 = blockIdx.x * 64;
  const int bk = blockIdx.y;
  const int b = bk >> 2, k = bk & 3;
  const int tid = threadIdx.x;
  const int tx = tid & 15, ty = tid >> 4;
  __shared__ __align__(16) float As[16][64];
  __shared__ __align__(16) float Bs[16][64];
  float acc[4][4] = {};
  const float* src = ((k & 1) ? xcT : xc) + (size_t)b * 384 * L;
  const bool rev = (k >= 2);
  const float* ap = xpw + (size_t)k * 44 * 384;
  for (int c0 = 0; c0 < 384; c0 += 16) {
    {
      const int mm = tid & 63, kq = tid >> 6;
      float4 a = make_float4(0.f, 0.f, 0.f, 0.f);
      if (mm < 44) a = *(const float4*)&ap[(size_t)mm * 384 + c0 + kq * 4];
      As[kq * 4 + 0][mm] = a.x; As[kq * 4 + 1][mm] = a.y;
      As[kq * 4 + 2][mm] = a.z; As[kq * 4 + 3][mm] = a.w;
    }
    {
      const int n4 = (tid & 15) * 4, kk = tid >> 4;
      const float* sr = src + (size_t)(c0 + kk) * L;
      float4 v;
      if (!rev) {
        v = *(const float4*)&sr[n0 + n4];
      } else {
        float4 t = *(const float4*)&sr[2300 - n0 - n4];
        v = make_float4(t.w, t.z, t.y, t.x);
      }
      *(float4*)&Bs[kk][n4] = v;
    }
    __syncthreads();
#pragma unroll
    for (int kk = 0; kk < 16; ++kk) {
      float4 a4 = *(const float4*)&As[kk][ty * 4];
      float4 b4 = *(const float4*)&Bs[kk][tx * 4];
      float av[4] = {a4.x, a4.y, a4.z, a4.w};
      float bv[4] = {b4.x, b4.y, b4.z, b4.w};
#pragma unroll
      for (int i = 0; i < 4; ++i)
#pragma unroll
        for (int j = 0; j < 4; ++j) acc[i][j] = fmaf(av[i], bv[j], acc[i][j]);
    }
    __syncthreads();
  }
#pragma unroll
  for (int i = 0; i < 4; ++i) {
    int m = ty * 4 + i;
    if (m < 44) {
      float4 v = make_float4(acc[i][0], acc[i][1], acc[i][2], acc[i][3]);
      *(float4*)&xdbl[((size_t)bk * 48 + m) * L + n0 + tx * 4] = v;
    }
  }
}

// ---------------------------------------------------------------- scan
__global__ __launch_bounds__(256) void k_scan(const float* __restrict__ xc,
                                              const float* __restrict__ xcT,
                                              const float* __restrict__ xdbl,
                                              const float* __restrict__ dt_w,
                                              const float* __restrict__ dt_b,
                                              const float* __restrict__ A_logs,
                                              const float* __restrict__ Ds,
                                              float* __restrict__ ys) {
  const int bid = blockIdx.x;
  const int dg = bid % 24;
  const int k = (bid / 24) % 4;
  const int b = bid / 96;
  const int tid = threadIdx.x;
  const int lane = tid & 63, wv = tid >> 6;
  const int n = lane & 15;
  const int d_local = wv * 4 + (lane >> 4);
  const int d = dg * 16 + d_local;
  const int kd = k * 384 + d;
  const float A2 = -__expf(A_logs[(size_t)kd * 16 + n]) * 1.44269504088896f;
  const float Dskip = Ds[kd];
  const float* src = ((k & 1) ? xcT : xc);
  const float* usrc = src + ((size_t)b * 384 + d) * L;
  const bool rev = (k >= 2);
  // delta compute-phase role: lanes over t so loads coalesce
  const int tc = tid & 15, dc = tid >> 4;
  float dtw[12];
  const float* dwp = dt_w + (size_t)(k * 384 + dg * 16 + dc) * 12;
#pragma unroll
  for (int r = 0; r < 12; ++r) dtw[r] = dwp[r];
  const float dtb = dt_b[k * 384 + dg * 16 + dc];
  const float* ucs = src + ((size_t)b * 384 + dg * 16 + dc) * L;
  const float* xd = xdbl + (size_t)(b * 4 + k) * 48 * L;
  float* ysp = ys + (size_t)(b * 4 + k) * L * 384;

  __shared__ float dtr_s[12][64];
  __shared__ float2 dds[16][64];
  float h = 0.0f;
  for (int t0 = 0; t0 < L; t0 += 64) {
    for (int i = tid; i < 768; i += 256) {
      int r = i >> 6, c = i & 63;
      dtr_s[r][c] = xd[(size_t)r * L + t0 + c];
    }
    __syncthreads();
#pragma unroll
    for (int q = 0; q < 4; ++q) {
      int tl = tc + q * 16;
      float raw = dtb;
#pragma unroll
      for (int r = 0; r < 12; ++r) raw = fmaf(dtw[r], dtr_s[r][tl], raw);
      float sp = (raw > 20.0f) ? raw : log1pf(__expf(raw));
      int t = t0 + tl;
      float u = rev ? ucs[2303 - t] : ucs[t];
      dds[dc][tl] = make_float2(sp, sp * u);
    }
    __syncthreads();
    for (int s4 = 0; s4 < 64; s4 += 4) {
      const int t = t0 + s4;
      float4 b4 = *(const float4*)&xd[(size_t)(12 + n) * L + t];
      float4 c4 = *(const float4*)&xd[(size_t)(28 + n) * L + t];
      float4 u4 = make_float4(0.f, 0.f, 0.f, 0.f);
      if (n == 0) {
        if (!rev) {
          u4 = *(const float4*)&usrc[t];
        } else {
          float4 tmp = *(const float4*)&usrc[2300 - t];
          u4 = make_float4(tmp.w, tmp.z, tmp.y, tmp.x);
        }
      }
      float bv[4] = {b4.x, b4.y, b4.z, b4.w};
      float cv[4] = {c4.x, c4.y, c4.z, c4.w};
      float uv[4] = {u4.x, u4.y, u4.z, u4.w};
#pragma unroll
      for (int j = 0; j < 4; ++j) {
        float2 dd = dds[d_local][s4 + j];
        float dA = exp2f(dd.x * A2);
        h = fmaf(h, dA, dd.y * bv[j]);
        float yp = h * cv[j];
        yp += __shfl_xor(yp, 1);
        yp += __shfl_xor(yp, 2);
        yp += __shfl_xor(yp, 4);
        yp += __shfl_xor(yp, 8);
        if (n == 0) ysp[(size_t)(t + j) * 384 + d] = yp + uv[j] * Dskip;
      }
    }
    __syncthreads();
  }
}

// ---------------------------------------------------------------- merge+LN
__global__ __launch_bounds__(384) void k_merge(const float* __restrict__ ys,
                                               const float* __restrict__ z1T,
                                               const float* __restrict__ ln_w,
                                               const float* __restrict__ ln_b,
                                               float* __restrict__ yln) {
  const int b = blockIdx.x / L;
  const int l = blockIdx.x % L;
  const int d = threadIdx.x;
  const int hh = l / 48, ww = l % 48;
  const int j = ww * 48 + hh;
  const float* base = ys + (size_t)b * 4 * L * 384;
  float v = base[(size_t)(0 * L + l) * 384 + d] +
            base[(size_t)(1 * L + j) * 384 + d] +
            base[(size_t)(2 * L + (2303 - l)) * 384 + d] +
            base[(size_t)(3 * L + (2303 - j)) * 384 + d];
  float s1 = v, s2 = v * v;
#pragma unroll
  for (int off = 32; off; off >>= 1) {
    s1 += __shfl_xor(s1, off);
    s2 += __shfl_xor(s2, off);
  }
  __shared__ float ps1[6], ps2[6];
  const int wv = threadIdx.x >> 6;
  if ((threadIdx.x & 63) == 0) { ps1[wv] = s1; ps2[wv] = s2; }
  __syncthreads();
  float t1 = 0.f, t2 = 0.f;
#pragma unroll
  for (int i = 0; i < 6; ++i) { t1 += ps1[i]; t2 += ps2[i]; }
  const float mu = t1 * (1.0f / 384.0f);
  const float var = t2 * (1.0f / 384.0f) - mu * mu;
  const float rs = rsqrtf(var + 1e-5f);
  const float yv = (v - mu) * rs * ln_w[d] + ln_b[d];
  yln[((size_t)b * L + l) * 384 + d] = yv * z1T[((size_t)b * L + l) * 384 + d];
}

// ---------------------------------------------------------------- out_proj
__global__ __launch_bounds__(256) void k_outproj(const float* __restrict__ yln,
                                                 const float* __restrict__ W2,
                                                 float* __restrict__ out) {
  const int l0 = blockIdx.x * 64;
  const int c0 = blockIdx.y * 64;
  const int b = blockIdx.z;
  const int tid = threadIdx.x;
  const int tx = tid & 15, ty = tid >> 4;
  __shared__ __align__(16) float As[16][64];  // [kk][l]
  __shared__ __align__(16) float Bs[16][64];  // [kk][c]
  float acc[4][4] = {};
  const float* ybase = yln + (size_t)b * L * 384;
  for (int k0 = 0; k0 < 384; k0 += 16) {
    {
      const int mm = tid & 63, kq = tid >> 6;
      float4 a = *(const float4*)&ybase[(size_t)(l0 + mm) * 384 + k0 + kq * 4];
      As[kq * 4 + 0][mm] = a.x; As[kq * 4 + 1][mm] = a.y;
      As[kq * 4 + 2][mm] = a.z; As[kq * 4 + 3][mm] = a.w;
    }
    {
      const int nn = tid & 63, kq = tid >> 6;
      float4 w = *(const float4*)&W2[(size_t)(c0 + nn) * 384 + k0 + kq * 4];
      Bs[kq * 4 + 0][nn] = w.x; Bs[kq * 4 + 1][nn] = w.y;
      Bs[kq * 4 + 2][nn] = w.z; Bs[kq * 4 + 3][nn] = w.w;
    }
    __syncthreads();
#pragma unroll
    for (int kk = 0; kk < 16; ++kk) {
      float4 a4 = *(const float4*)&As[kk][tx * 4];  // l
      float4 b4 = *(const float4*)&Bs[kk][ty * 4];  // c
      float av[4] = {a4.x, a4.y, a4.z, a4.w};
      float bv[4] = {b4.x, b4.y, b4.z, b4.w};
#pragma unroll
      for (int i = 0; i < 4; ++i)
#pragma unroll
        for (int j = 0; j < 4; ++j) acc[i][j] = fmaf(bv[i], av[j], acc[i][j]);
    }
    __syncthreads();
  }
#pragma unroll
  for (int i = 0; i < 4; ++i) {
    float4 v = make_float4(acc[i][0], acc[i][1], acc[i][2], acc[i][3]);
    *(float4*)&out[((size_t)b * 192 + c0 + ty * 4 + i) * L + l0 + tx * 4] = v;
  }
}

// ---------------------------------------------------------------- launch
extern "C" void kernel_launch(void* const* d_in, const int* in_sizes, int n_in,
                              void* d_out, int out_size, void* d_ws, size_t ws_size,
                              hipStream_t stream) {
  const float* x = (const float*)d_in[0];
  const float* in_proj_w = (const float*)d_in[1];
  const float* conv_w = (const float*)d_in[2];
  const float* conv_b = (const float*)d_in[3];
  const float* x_proj_w = (const float*)d_in[4];
  const float* dt_w = (const float*)d_in[5];
  const float* dt_b = (const float*)d_in[6];
  const float* A_logs = (const float*)d_in[7];
  const float* Ds = (const float*)d_in[8];
  const float* ln_w = (const float*)d_in[9];
  const float* ln_b = (const float*)d_in[10];
  const float* out_proj_w = (const float*)d_in[11];
  float* out = (float*)d_out;
  float* ws = (float*)d_ws;

  const size_t SZ_BDL = (size_t)8 * 384 * L;  // 7,077,888
  float* xx = ws;                      // (B,384,L), later reused as yln
  float* z1T = xx + SZ_BDL;            // (B,L,384)
  float* xconv = z1T + SZ_BDL;         // (B,384,L) hw
  float* xconvT = xconv + SZ_BDL;      // (B,384,L) wh
  float* xdbl = xconvT + SZ_BDL;       // (B,4,48,L)
  float* ys = xdbl + (size_t)8 * 4 * 48 * L;  // (B,4,L,384)
  float* yln = xx;                     // alias (xx dead after conv)

  k_inproj<<<dim3(36, 12, 8), 256, 0, stream>>>(x, in_proj_w, xx, z1T);
  k_conv<<<dim3(3072), 256, 0, stream>>>(xx, conv_w, conv_b, xconv, xconvT);
  k_xdbl<<<dim3(36, 32), 256, 0, stream>>>(xconv, xconvT, x_proj_w, xdbl);
  k_scan<<<dim3(768), 256, 0, stream>>>(xconv, xconvT, xdbl, dt_w, dt_b,
                                        A_logs, Ds, ys);
  k_merge<<<dim3(8 * L), 384, 0, stream>>>(ys, z1T, ln_w, ln_b, yln);
  k_outproj<<<dim3(36, 3, 8), 256, 0, stream>>>(yln, out_proj_w, out);
}

// Round 2
// 874.273 us; speedup vs baseline: 1.2336x; 1.2336x over previous
//
#include <hip/hip_runtime.h>
#include <cstdint>

// SS2D forward. Round 2: k_scan restructured — DPP row-reduce (no LDS
// bpermute), 4-step batched float4 reads of dds/B/C, store lane = n==15.
// B=8 C=192 H=W=48 L=2304 D_EXP=D_INNER=384 K=4 N=16 R=12

static constexpr int L = 2304;

__device__ __forceinline__ float gelu_f(float x) {
  return 0.5f * x * (1.0f + erff(x * 0.70710678118654752440f));
}

// Sum over each 16-lane row; result valid in lane (lane&15)==15.
__device__ __forceinline__ float rowsum16(float v) {
  v += __int_as_float(__builtin_amdgcn_update_dpp(
      0, __float_as_int(v), 0x111, 0xF, 0xF, true));  // row_shr:1
  v += __int_as_float(__builtin_amdgcn_update_dpp(
      0, __float_as_int(v), 0x112, 0xF, 0xF, true));  // row_shr:2
  v += __int_as_float(__builtin_amdgcn_update_dpp(
      0, __float_as_int(v), 0x114, 0xF, 0xF, true));  // row_shr:4
  v += __int_as_float(__builtin_amdgcn_update_dpp(
      0, __float_as_int(v), 0x118, 0xF, 0xF, true));  // row_shr:8
  return v;
}

// ---------------------------------------------------------------- in_proj
__global__ __launch_bounds__(256) void k_inproj(const float* __restrict__ x,
                                                const float* __restrict__ Wp,
                                                float* __restrict__ xx,
                                                float* __restrict__ z1T) {
  const int b = blockIdx.z;
  const int m0 = blockIdx.y * 64;   // output channel tile (0..768)
  const int n0 = blockIdx.x * 64;   // l tile
  const int tid = threadIdx.x;
  const int tx = tid & 15, ty = tid >> 4;
  __shared__ __align__(16) float As[16][64];
  __shared__ __align__(16) float Bs[16][64];
  __shared__ __align__(16) float zt[64][68];
  float acc[4][4] = {};
  const float* xb = x + (size_t)b * 192 * L;
  for (int c0 = 0; c0 < 192; c0 += 16) {
    {
      const int mm = tid & 63, kq = tid >> 6;
      float4 a = *(const float4*)&Wp[(size_t)(m0 + mm) * 192 + c0 + kq * 4];
      As[kq * 4 + 0][mm] = a.x; As[kq * 4 + 1][mm] = a.y;
      As[kq * 4 + 2][mm] = a.z; As[kq * 4 + 3][mm] = a.w;
    }
    {
      const int n4 = (tid & 15) * 4, kk = tid >> 4;
      *(float4*)&Bs[kk][n4] = *(const float4*)&xb[(size_t)(c0 + kk) * L + n0 + n4];
    }
    __syncthreads();
#pragma unroll
    for (int kk = 0; kk < 16; ++kk) {
      float4 a4 = *(const float4*)&As[kk][ty * 4];
      float4 b4 = *(const float4*)&Bs[kk][tx * 4];
      float av[4] = {a4.x, a4.y, a4.z, a4.w};
      float bv[4] = {b4.x, b4.y, b4.z, b4.w};
#pragma unroll
      for (int i = 0; i < 4; ++i)
#pragma unroll
        for (int j = 0; j < 4; ++j) acc[i][j] = fmaf(av[i], bv[j], acc[i][j]);
    }
    __syncthreads();
  }
  if (m0 < 384) {
#pragma unroll
    for (int i = 0; i < 4; ++i) {
      int m = m0 + ty * 4 + i;
      float4 v = make_float4(acc[i][0], acc[i][1], acc[i][2], acc[i][3]);
      *(float4*)&xx[((size_t)b * 384 + m) * L + n0 + tx * 4] = v;
    }
  } else {
#pragma unroll
    for (int i = 0; i < 4; ++i)
#pragma unroll
      for (int j = 0; j < 4; ++j) zt[tx * 4 + j][ty * 4 + i] = gelu_f(acc[i][j]);
    __syncthreads();
    const int r = tid >> 2, cb = (tid & 3) * 16;
#pragma unroll
    for (int q = 0; q < 4; ++q) {
      int c = cb + q * 4;
      float4 v = make_float4(zt[r][c], zt[r][c + 1], zt[r][c + 2], zt[r][c + 3]);
      *(float4*)&z1T[((size_t)b * L + n0 + r) * 384 + (m0 - 384) + c] = v;
    }
  }
}

// ---------------------------------------------------------------- dw conv
__global__ __launch_bounds__(256) void k_conv(const float* __restrict__ xx,
                                              const float* __restrict__ conv_w,
                                              const float* __restrict__ conv_b,
                                              float* __restrict__ xc,
                                              float* __restrict__ xcT) {
  const int bid = blockIdx.x;
  const int d = bid % 384, b = bid / 384;
  const int tid = threadIdx.x;
  __shared__ float ls[48 * 49];
  __shared__ float xg[48 * 49];
  const float* src = xx + ((size_t)b * 384 + d) * L;
  for (int i = tid; i < L; i += 256) ls[(i / 48) * 49 + (i % 48)] = src[i];
  float cw[9];
  const float* cwp = conv_w + (size_t)d * 9;
#pragma unroll
  for (int r = 0; r < 9; ++r) cw[r] = cwp[r];
  const float cb = conv_b[d];
  __syncthreads();
  float* dst = xc + ((size_t)b * 384 + d) * L;
  for (int p = tid; p < L; p += 256) {
    int h = p / 48, w = p % 48;
    float acc = cb;
#pragma unroll
    for (int dy = -1; dy <= 1; ++dy) {
      int hh = h + dy;
      if (hh < 0 || hh >= 48) continue;
#pragma unroll
      for (int dx = -1; dx <= 1; ++dx) {
        int ww = w + dx;
        if (ww < 0 || ww >= 48) continue;
        acc = fmaf(ls[hh * 49 + ww], cw[(dy + 1) * 3 + (dx + 1)], acc);
      }
    }
    float g = gelu_f(acc);
    dst[p] = g;
    xg[h * 49 + w] = g;
  }
  __syncthreads();
  float* dstT = xcT + ((size_t)b * 384 + d) * L;
  for (int j = tid; j < L; j += 256) {
    int h = j % 48, w = j / 48;
    dstT[j] = xg[h * 49 + w];
  }
}

// ---------------------------------------------------------------- x_proj
__global__ __launch_bounds__(256) void k_xdbl(const float* __restrict__ xc,
                                              const float* __restrict__ xcT,
                                              const float* __restrict__ xpw,
                                              float* __restrict__ xdbl) {
  const int n0 = blockIdx.x * 64;
  const int bk = blockIdx.y;
  const int b = bk >> 2, k = bk & 3;
  const int tid = threadIdx.x;
  const int tx = tid & 15, ty = tid >> 4;
  __shared__ __align__(16) float As[16][64];
  __shared__ __align__(16) float Bs[16][64];
  float acc[4][4] = {};
  const float* src = ((k & 1) ? xcT : xc) + (size_t)b * 384 * L;
  const bool rev = (k >= 2);
  const float* ap = xpw + (size_t)k * 44 * 384;
  for (int c0 = 0; c0 < 384; c0 += 16) {
    {
      const int mm = tid & 63, kq = tid >> 6;
      float4 a = make_float4(0.f, 0.f, 0.f, 0.f);
      if (mm < 44) a = *(const float4*)&ap[(size_t)mm * 384 + c0 + kq * 4];
      As[kq * 4 + 0][mm] = a.x; As[kq * 4 + 1][mm] = a.y;
      As[kq * 4 + 2][mm] = a.z; As[kq * 4 + 3][mm] = a.w;
    }
    {
      const int n4 = (tid & 15) * 4, kk = tid >> 4;
      const float* sr = src + (size_t)(c0 + kk) * L;
      float4 v;
      if (!rev) {
        v = *(const float4*)&sr[n0 + n4];
      } else {
        float4 t = *(const float4*)&sr[2300 - n0 - n4];
        v = make_float4(t.w, t.z, t.y, t.x);
      }
      *(float4*)&Bs[kk][n4] = v;
    }
    __syncthreads();
#pragma unroll
    for (int kk = 0; kk < 16; ++kk) {
      float4 a4 = *(const float4*)&As[kk][ty * 4];
      float4 b4 = *(const float4*)&Bs[kk][tx * 4];
      float av[4] = {a4.x, a4.y, a4.z, a4.w};
      float bv[4] = {b4.x, b4.y, b4.z, b4.w};
#pragma unroll
      for (int i = 0; i < 4; ++i)
#pragma unroll
        for (int j = 0; j < 4; ++j) acc[i][j] = fmaf(av[i], bv[j], acc[i][j]);
    }
    __syncthreads();
  }
#pragma unroll
  for (int i = 0; i < 4; ++i) {
    int m = ty * 4 + i;
    if (m < 44) {
      float4 v = make_float4(acc[i][0], acc[i][1], acc[i][2], acc[i][3]);
      *(float4*)&xdbl[((size_t)bk * 48 + m) * L + n0 + tx * 4] = v;
    }
  }
}

// ---------------------------------------------------------------- scan
__global__ __launch_bounds__(256) void k_scan(const float* __restrict__ xc,
                                              const float* __restrict__ xcT,
                                              const float* __restrict__ xdbl,
                                              const float* __restrict__ dt_w,
                                              const float* __restrict__ dt_b,
                                              const float* __restrict__ A_logs,
                                              const float* __restrict__ Ds,
                                              float* __restrict__ ys) {
  const int bid = blockIdx.x;
  const int dg = bid % 24;
  const int k = (bid / 24) % 4;
  const int b = bid / 96;
  const int tid = threadIdx.x;
  const int lane = tid & 63, wv = tid >> 6;
  const int n = lane & 15;
  const int d_local = wv * 4 + (lane >> 4);
  const int d = dg * 16 + d_local;
  const int kd = k * 384 + d;
  const float A2 = -__expf(A_logs[(size_t)kd * 16 + n]) * 1.44269504088896f;
  const float Dskip = Ds[kd];
  const float* src = ((k & 1) ? xcT : xc);
  const float* usrc = src + ((size_t)b * 384 + d) * L;
  const bool rev = (k >= 2);
  // delta compute-phase role: lanes over t so loads coalesce
  const int tc = tid & 15, dc = tid >> 4;
  float dtw[12];
  const float* dwp = dt_w + (size_t)(k * 384 + dg * 16 + dc) * 12;
#pragma unroll
  for (int r = 0; r < 12; ++r) dtw[r] = dwp[r];
  const float dtb = dt_b[k * 384 + dg * 16 + dc];
  const float* ucs = src + ((size_t)b * 384 + dg * 16 + dc) * L;
  const float* xd = xdbl + (size_t)(b * 4 + k) * 48 * L;
  const float* Brow = xd + (size_t)(12 + n) * L;
  const float* Crow = xd + (size_t)(28 + n) * L;
  float* ysp = ys + (size_t)(b * 4 + k) * L * 384;

  __shared__ float dtr_s[12][64];
  __shared__ __align__(16) float dds[16][128];  // per d row: (sp, sp*u) pairs
  float h = 0.0f;
  const bool red_lane = (n == 15);  // rowsum16 result lands here
  for (int t0 = 0; t0 < L; t0 += 64) {
    for (int i = tid; i < 768; i += 256) {
      int r = i >> 6, c = i & 63;
      dtr_s[r][c] = xd[(size_t)r * L + t0 + c];
    }
    __syncthreads();
#pragma unroll
    for (int q = 0; q < 4; ++q) {
      int tl = tc + q * 16;
      float raw = dtb;
#pragma unroll
      for (int r = 0; r < 12; ++r) raw = fmaf(dtw[r], dtr_s[r][tl], raw);
      float sp = (raw > 20.0f) ? raw : log1pf(__expf(raw));
      int t = t0 + tl;
      float u = rev ? ucs[2303 - t] : ucs[t];
      ((float2*)dds[dc])[tl] = make_float2(sp, sp * u);
    }
    __syncthreads();
    const float* ddr = dds[d_local];
#pragma unroll
    for (int s4 = 0; s4 < 64; s4 += 4) {
      const int t = t0 + s4;
      float4 b4 = *(const float4*)&Brow[t];
      float4 c4 = *(const float4*)&Crow[t];
      float4 p01 = *(const float4*)&ddr[2 * s4];      // sp0, spu0, sp1, spu1
      float4 p23 = *(const float4*)&ddr[2 * s4 + 4];  // sp2, spu2, sp3, spu3
      float4 u4 = make_float4(0.f, 0.f, 0.f, 0.f);
      if (red_lane) {
        if (!rev) {
          u4 = *(const float4*)&usrc[t];
        } else {
          float4 tmp = *(const float4*)&usrc[2300 - t];
          u4 = make_float4(tmp.w, tmp.z, tmp.y, tmp.x);
        }
      }
      // 4 independent exps up front (ILP), then the short serial h-chain
      float e0 = exp2f(p01.x * A2);
      float e1 = exp2f(p01.z * A2);
      float e2 = exp2f(p23.x * A2);
      float e3 = exp2f(p23.z * A2);
      h = fmaf(h, e0, p01.y * b4.x);
      float y0 = h * c4.x;
      h = fmaf(h, e1, p01.w * b4.y);
      float y1 = h * c4.y;
      h = fmaf(h, e2, p23.y * b4.z);
      float y2 = h * c4.z;
      h = fmaf(h, e3, p23.w * b4.w);
      float y3 = h * c4.w;
      y0 = rowsum16(y0);
      y1 = rowsum16(y1);
      y2 = rowsum16(y2);
      y3 = rowsum16(y3);
      if (red_lane) {
        ysp[(size_t)(t + 0) * 384 + d] = y0 + u4.x * Dskip;
        ysp[(size_t)(t + 1) * 384 + d] = y1 + u4.y * Dskip;
        ysp[(size_t)(t + 2) * 384 + d] = y2 + u4.z * Dskip;
        ysp[(size_t)(t + 3) * 384 + d] = y3 + u4.w * Dskip;
      }
    }
    __syncthreads();
  }
}

// ---------------------------------------------------------------- merge+LN
__global__ __launch_bounds__(384) void k_merge(const float* __restrict__ ys,
                                               const float* __restrict__ z1T,
                                               const float* __restrict__ ln_w,
                                               const float* __restrict__ ln_b,
                                               float* __restrict__ yln) {
  const int b = blockIdx.x / L;
  const int l = blockIdx.x % L;
  const int d = threadIdx.x;
  const int hh = l / 48, ww = l % 48;
  const int j = ww * 48 + hh;
  const float* base = ys + (size_t)b * 4 * L * 384;
  float v = base[(size_t)(0 * L + l) * 384 + d] +
            base[(size_t)(1 * L + j) * 384 + d] +
            base[(size_t)(2 * L + (2303 - l)) * 384 + d] +
            base[(size_t)(3 * L + (2303 - j)) * 384 + d];
  float s1 = v, s2 = v * v;
#pragma unroll
  for (int off = 32; off; off >>= 1) {
    s1 += __shfl_xor(s1, off);
    s2 += __shfl_xor(s2, off);
  }
  __shared__ float ps1[6], ps2[6];
  const int wv = threadIdx.x >> 6;
  if ((threadIdx.x & 63) == 0) { ps1[wv] = s1; ps2[wv] = s2; }
  __syncthreads();
  float t1 = 0.f, t2 = 0.f;
#pragma unroll
  for (int i = 0; i < 6; ++i) { t1 += ps1[i]; t2 += ps2[i]; }
  const float mu = t1 * (1.0f / 384.0f);
  const float var = t2 * (1.0f / 384.0f) - mu * mu;
  const float rs = rsqrtf(var + 1e-5f);
  const float yv = (v - mu) * rs * ln_w[d] + ln_b[d];
  yln[((size_t)b * L + l) * 384 + d] = yv * z1T[((size_t)b * L + l) * 384 + d];
}

// ---------------------------------------------------------------- out_proj
__global__ __launch_bounds__(256) void k_outproj(const float* __restrict__ yln,
                                                 const float* __restrict__ W2,
                                                 float* __restrict__ out) {
  const int l0 = blockIdx.x * 64;
  const int c0 = blockIdx.y * 64;
  const int b = blockIdx.z;
  const int tid = threadIdx.x;
  const int tx = tid & 15, ty = tid >> 4;
  __shared__ __align__(16) float As[16][64];  // [kk][l]
  __shared__ __align__(16) float Bs[16][64];  // [kk][c]
  float acc[4][4] = {};
  const float* ybase = yln + (size_t)b * L * 384;
  for (int k0 = 0; k0 < 384; k0 += 16) {
    {
      const int mm = tid & 63, kq = tid >> 6;
      float4 a = *(const float4*)&ybase[(size_t)(l0 + mm) * 384 + k0 + kq * 4];
      As[kq * 4 + 0][mm] = a.x; As[kq * 4 + 1][mm] = a.y;
      As[kq * 4 + 2][mm] = a.z; As[kq * 4 + 3][mm] = a.w;
    }
    {
      const int nn = tid & 63, kq = tid >> 6;
      float4 w = *(const float4*)&W2[(size_t)(c0 + nn) * 384 + k0 + kq * 4];
      Bs[kq * 4 + 0][nn] = w.x; Bs[kq * 4 + 1][nn] = w.y;
      Bs[kq * 4 + 2][nn] = w.z; Bs[kq * 4 + 3][nn] = w.w;
    }
    __syncthreads();
#pragma unroll
    for (int kk = 0; kk < 16; ++kk) {
      float4 a4 = *(const float4*)&As[kk][tx * 4];  // l
      float4 b4 = *(const float4*)&Bs[kk][ty * 4];  // c
      float av[4] = {a4.x, a4.y, a4.z, a4.w};
      float bv[4] = {b4.x, b4.y, b4.z, b4.w};
#pragma unroll
      for (int i = 0; i < 4; ++i)
#pragma unroll
        for (int j = 0; j < 4; ++j) acc[i][j] = fmaf(bv[i], av[j], acc[i][j]);
    }
    __syncthreads();
  }
#pragma unroll
  for (int i = 0; i < 4; ++i) {
    float4 v = make_float4(acc[i][0], acc[i][1], acc[i][2], acc[i][3]);
    *(float4*)&out[((size_t)b * 192 + c0 + ty * 4 + i) * L + l0 + tx * 4] = v;
  }
}

// ---------------------------------------------------------------- launch
extern "C" void kernel_launch(void* const* d_in, const int* in_sizes, int n_in,
                              void* d_out, int out_size, void* d_ws, size_t ws_size,
                              hipStream_t stream) {
  const float* x = (const float*)d_in[0];
  const float* in_proj_w = (const float*)d_in[1];
  const float* conv_w = (const float*)d_in[2];
  const float* conv_b = (const float*)d_in[3];
  const float* x_proj_w = (const float*)d_in[4];
  const float* dt_w = (const float*)d_in[5];
  const float* dt_b = (const float*)d_in[6];
  const float* A_logs = (const float*)d_in[7];
  const float* Ds = (const float*)d_in[8];
  const float* ln_w = (const float*)d_in[9];
  const float* ln_b = (const float*)d_in[10];
  const float* out_proj_w = (const float*)d_in[11];
  float* out = (float*)d_out;
  float* ws = (float*)d_ws;

  const size_t SZ_BDL = (size_t)8 * 384 * L;  // 7,077,888
  float* xx = ws;                      // (B,384,L), later reused as yln
  float* z1T = xx + SZ_BDL;            // (B,L,384)
  float* xconv = z1T + SZ_BDL;         // (B,384,L) hw
  float* xconvT = xconv + SZ_BDL;      // (B,384,L) wh
  float* xdbl = xconvT + SZ_BDL;       // (B,4,48,L)
  float* ys = xdbl + (size_t)8 * 4 * 48 * L;  // (B,4,L,384)
  float* yln = xx;                     // alias (xx dead after conv)

  k_inproj<<<dim3(36, 12, 8), 256, 0, stream>>>(x, in_proj_w, xx, z1T);
  k_conv<<<dim3(3072), 256, 0, stream>>>(xx, conv_w, conv_b, xconv, xconvT);
  k_xdbl<<<dim3(36, 32), 256, 0, stream>>>(xconv, xconvT, x_proj_w, xdbl);
  k_scan<<<dim3(768), 256, 0, stream>>>(xconv, xconvT, xdbl, dt_w, dt_b,
                                        A_logs, Ds, ys);
  k_merge<<<dim3(8 * L), 384, 0, stream>>>(ys, z1T, ln_w, ln_b, yln);
  k_outproj<<<dim3(36, 3, 8), 256, 0, stream>>>(yln, out_proj_w, out);
}

// Round 3
// 608.825 us; speedup vs baseline: 1.7715x; 1.4360x over previous
//
#include <hip/hip_runtime.h>
#include <cstdint>

// SS2D forward. Round 3: k_scan made LDS-resident — all 44 xdbl rows staged
// per 64-chunk (padded, conflict-free), u staged in LDS, dds padded to 132,
// delta phase vectorized (b128 reads), launch_bounds(256,3) for VGPR headroom.
// B=8 C=192 H=W=48 L=2304 D_EXP=D_INNER=384 K=4 N=16 R=12

static constexpr int L = 2304;

__device__ __forceinline__ float gelu_f(float x) {
  return 0.5f * x * (1.0f + erff(x * 0.70710678118654752440f));
}

// Sum over each 16-lane row; result valid in lane (lane&15)==15.
__device__ __forceinline__ float rowsum16(float v) {
  v += __int_as_float(__builtin_amdgcn_update_dpp(
      0, __float_as_int(v), 0x111, 0xF, 0xF, true));  // row_shr:1
  v += __int_as_float(__builtin_amdgcn_update_dpp(
      0, __float_as_int(v), 0x112, 0xF, 0xF, true));  // row_shr:2
  v += __int_as_float(__builtin_amdgcn_update_dpp(
      0, __float_as_int(v), 0x114, 0xF, 0xF, true));  // row_shr:4
  v += __int_as_float(__builtin_amdgcn_update_dpp(
      0, __float_as_int(v), 0x118, 0xF, 0xF, true));  // row_shr:8
  return v;
}

// ---------------------------------------------------------------- in_proj
__global__ __launch_bounds__(256) void k_inproj(const float* __restrict__ x,
                                                const float* __restrict__ Wp,
                                                float* __restrict__ xx,
                                                float* __restrict__ z1T) {
  const int b = blockIdx.z;
  const int m0 = blockIdx.y * 64;   // output channel tile (0..768)
  const int n0 = blockIdx.x * 64;   // l tile
  const int tid = threadIdx.x;
  const int tx = tid & 15, ty = tid >> 4;
  __shared__ __align__(16) float As[16][64];
  __shared__ __align__(16) float Bs[16][64];
  __shared__ __align__(16) float zt[64][68];
  float acc[4][4] = {};
  const float* xb = x + (size_t)b * 192 * L;
  for (int c0 = 0; c0 < 192; c0 += 16) {
    {
      const int mm = tid & 63, kq = tid >> 6;
      float4 a = *(const float4*)&Wp[(size_t)(m0 + mm) * 192 + c0 + kq * 4];
      As[kq * 4 + 0][mm] = a.x; As[kq * 4 + 1][mm] = a.y;
      As[kq * 4 + 2][mm] = a.z; As[kq * 4 + 3][mm] = a.w;
    }
    {
      const int n4 = (tid & 15) * 4, kk = tid >> 4;
      *(float4*)&Bs[kk][n4] = *(const float4*)&xb[(size_t)(c0 + kk) * L + n0 + n4];
    }
    __syncthreads();
#pragma unroll
    for (int kk = 0; kk < 16; ++kk) {
      float4 a4 = *(const float4*)&As[kk][ty * 4];
      float4 b4 = *(const float4*)&Bs[kk][tx * 4];
      float av[4] = {a4.x, a4.y, a4.z, a4.w};
      float bv[4] = {b4.x, b4.y, b4.z, b4.w};
#pragma unroll
      for (int i = 0; i < 4; ++i)
#pragma unroll
        for (int j = 0; j < 4; ++j) acc[i][j] = fmaf(av[i], bv[j], acc[i][j]);
    }
    __syncthreads();
  }
  if (m0 < 384) {
#pragma unroll
    for (int i = 0; i < 4; ++i) {
      int m = m0 + ty * 4 + i;
      float4 v = make_float4(acc[i][0], acc[i][1], acc[i][2], acc[i][3]);
      *(float4*)&xx[((size_t)b * 384 + m) * L + n0 + tx * 4] = v;
    }
  } else {
#pragma unroll
    for (int i = 0; i < 4; ++i)
#pragma unroll
      for (int j = 0; j < 4; ++j) zt[tx * 4 + j][ty * 4 + i] = gelu_f(acc[i][j]);
    __syncthreads();
    const int r = tid >> 2, cb = (tid & 3) * 16;
#pragma unroll
    for (int q = 0; q < 4; ++q) {
      int c = cb + q * 4;
      float4 v = make_float4(zt[r][c], zt[r][c + 1], zt[r][c + 2], zt[r][c + 3]);
      *(float4*)&z1T[((size_t)b * L + n0 + r) * 384 + (m0 - 384) + c] = v;
    }
  }
}

// ---------------------------------------------------------------- dw conv
__global__ __launch_bounds__(256) void k_conv(const float* __restrict__ xx,
                                              const float* __restrict__ conv_w,
                                              const float* __restrict__ conv_b,
                                              float* __restrict__ xc,
                                              float* __restrict__ xcT) {
  const int bid = blockIdx.x;
  const int d = bid % 384, b = bid / 384;
  const int tid = threadIdx.x;
  __shared__ float ls[48 * 49];
  __shared__ float xg[48 * 49];
  const float* src = xx + ((size_t)b * 384 + d) * L;
  for (int i = tid; i < L; i += 256) ls[(i / 48) * 49 + (i % 48)] = src[i];
  float cw[9];
  const float* cwp = conv_w + (size_t)d * 9;
#pragma unroll
  for (int r = 0; r < 9; ++r) cw[r] = cwp[r];
  const float cb = conv_b[d];
  __syncthreads();
  float* dst = xc + ((size_t)b * 384 + d) * L;
  for (int p = tid; p < L; p += 256) {
    int h = p / 48, w = p % 48;
    float acc = cb;
#pragma unroll
    for (int dy = -1; dy <= 1; ++dy) {
      int hh = h + dy;
      if (hh < 0 || hh >= 48) continue;
#pragma unroll
      for (int dx = -1; dx <= 1; ++dx) {
        int ww = w + dx;
        if (ww < 0 || ww >= 48) continue;
        acc = fmaf(ls[hh * 49 + ww], cw[(dy + 1) * 3 + (dx + 1)], acc);
      }
    }
    float g = gelu_f(acc);
    dst[p] = g;
    xg[h * 49 + w] = g;
  }
  __syncthreads();
  float* dstT = xcT + ((size_t)b * 384 + d) * L;
  for (int j = tid; j < L; j += 256) {
    int h = j % 48, w = j / 48;
    dstT[j] = xg[h * 49 + w];
  }
}

// ---------------------------------------------------------------- x_proj
__global__ __launch_bounds__(256) void k_xdbl(const float* __restrict__ xc,
                                              const float* __restrict__ xcT,
                                              const float* __restrict__ xpw,
                                              float* __restrict__ xdbl) {
  const int n0 = blockIdx.x * 64;
  const int bk = blockIdx.y;
  const int b = bk >> 2, k = bk & 3;
  const int tid = threadIdx.x;
  const int tx = tid & 15, ty = tid >> 4;
  __shared__ __align__(16) float As[16][64];
  __shared__ __align__(16) float Bs[16][64];
  float acc[4][4] = {};
  const float* src = ((k & 1) ? xcT : xc) + (size_t)b * 384 * L;
  const bool rev = (k >= 2);
  const float* ap = xpw + (size_t)k * 44 * 384;
  for (int c0 = 0; c0 < 384; c0 += 16) {
    {
      const int mm = tid & 63, kq = tid >> 6;
      float4 a = make_float4(0.f, 0.f, 0.f, 0.f);
      if (mm < 44) a = *(const float4*)&ap[(size_t)mm * 384 + c0 + kq * 4];
      As[kq * 4 + 0][mm] = a.x; As[kq * 4 + 1][mm] = a.y;
      As[kq * 4 + 2][mm] = a.z; As[kq * 4 + 3][mm] = a.w;
    }
    {
      const int n4 = (tid & 15) * 4, kk = tid >> 4;
      const float* sr = src + (size_t)(c0 + kk) * L;
      float4 v;
      if (!rev) {
        v = *(const float4*)&sr[n0 + n4];
      } else {
        float4 t = *(const float4*)&sr[2300 - n0 - n4];
        v = make_float4(t.w, t.z, t.y, t.x);
      }
      *(float4*)&Bs[kk][n4] = v;
    }
    __syncthreads();
#pragma unroll
    for (int kk = 0; kk < 16; ++kk) {
      float4 a4 = *(const float4*)&As[kk][ty * 4];
      float4 b4 = *(const float4*)&Bs[kk][tx * 4];
      float av[4] = {a4.x, a4.y, a4.z, a4.w};
      float bv[4] = {b4.x, b4.y, b4.z, b4.w};
#pragma unroll
      for (int i = 0; i < 4; ++i)
#pragma unroll
        for (int j = 0; j < 4; ++j) acc[i][j] = fmaf(av[i], bv[j], acc[i][j]);
    }
    __syncthreads();
  }
#pragma unroll
  for (int i = 0; i < 4; ++i) {
    int m = ty * 4 + i;
    if (m < 44) {
      float4 v = make_float4(acc[i][0], acc[i][1], acc[i][2], acc[i][3]);
      *(float4*)&xdbl[((size_t)bk * 48 + m) * L + n0 + tx * 4] = v;
    }
  }
}

// ---------------------------------------------------------------- scan
__global__ __launch_bounds__(256, 3) void k_scan(const float* __restrict__ xc,
                                                 const float* __restrict__ xcT,
                                                 const float* __restrict__ xdbl,
                                                 const float* __restrict__ dt_w,
                                                 const float* __restrict__ dt_b,
                                                 const float* __restrict__ A_logs,
                                                 const float* __restrict__ Ds,
                                                 float* __restrict__ ys) {
  const int bid = blockIdx.x;
  const int dg = bid % 24;
  const int k = (bid / 24) % 4;
  const int b = bid / 96;
  const int tid = threadIdx.x;
  const int lane = tid & 63, wv = tid >> 6;
  const int n = lane & 15;
  const int d_local = wv * 4 + (lane >> 4);
  const int d = dg * 16 + d_local;
  const int kd = k * 384 + d;
  const float A2 = -__expf(A_logs[(size_t)kd * 16 + n]) * 1.44269504088896f;
  const float Dskip = Ds[kd];
  const bool rev = (k >= 2);
  const float* src = ((k & 1) ? xcT : xc);
  // delta-phase role: thread (dc, tc) handles d=dg*16+dc, t = t0 + 4*tc + q
  const int tc = tid & 15, dc = tid >> 4;
  float dtw[12];
  const float* dwp = dt_w + (size_t)(k * 384 + dg * 16 + dc) * 12;
#pragma unroll
  for (int r = 0; r < 12; ++r) dtw[r] = dwp[r];
  const float dtb = dt_b[k * 384 + dg * 16 + dc];
  const float* ucs = src + ((size_t)b * 384 + dg * 16 + dc) * L;
  const float* xd = xdbl + (size_t)(b * 4 + k) * 48 * L;
  float* ysp = ys + (size_t)(b * 4 + k) * L * 384 + d;  // this thread's column

  __shared__ __align__(16) float xs[44][68];   // xdbl rows for chunk (pad 68)
  __shared__ __align__(16) float dds[16][132]; // (sp, sp*u) pairs  (pad 132)
  __shared__ __align__(16) float us[16][68];   // u per (d,t)       (pad 68)

  float h = 0.0f;
  const bool red_lane = (n == 15);  // rowsum16 result lands here
  for (int t0 = 0; t0 < L; t0 += 64) {
    // ---- stage all 44 xdbl rows for this chunk (coalesced, 2-way-free banks)
#pragma unroll
    for (int it = 0; it < 11; ++it) {
      int i = tid + it * 256;
      int r = i >> 6, c = i & 63;
      xs[r][c] = xd[(size_t)r * L + t0 + c];
    }
    __syncthreads();
    // ---- delta phase: 4 consecutive t per thread, vectorized LDS reads
    {
      float raw0 = dtb, raw1 = dtb, raw2 = dtb, raw3 = dtb;
#pragma unroll
      for (int r = 0; r < 12; ++r) {
        float4 v = *(const float4*)&xs[r][4 * tc];
        raw0 = fmaf(dtw[r], v.x, raw0);
        raw1 = fmaf(dtw[r], v.y, raw1);
        raw2 = fmaf(dtw[r], v.z, raw2);
        raw3 = fmaf(dtw[r], v.w, raw3);
      }
      float sp0 = (raw0 > 20.0f) ? raw0 : log1pf(__expf(raw0));
      float sp1 = (raw1 > 20.0f) ? raw1 : log1pf(__expf(raw1));
      float sp2 = (raw2 > 20.0f) ? raw2 : log1pf(__expf(raw2));
      float sp3 = (raw3 > 20.0f) ? raw3 : log1pf(__expf(raw3));
      const int t = t0 + 4 * tc;
      float4 u4;
      if (!rev) {
        u4 = *(const float4*)&ucs[t];
      } else {
        float4 tmp = *(const float4*)&ucs[2300 - t];
        u4 = make_float4(tmp.w, tmp.z, tmp.y, tmp.x);
      }
      *(float4*)&dds[dc][8 * tc] = make_float4(sp0, sp0 * u4.x, sp1, sp1 * u4.y);
      *(float4*)&dds[dc][8 * tc + 4] = make_float4(sp2, sp2 * u4.z, sp3, sp3 * u4.w);
      *(float4*)&us[dc][4 * tc] = u4;
    }
    __syncthreads();
    // ---- scan phase: 4 steps per batch, all operands LDS-resident
#pragma unroll
    for (int s4 = 0; s4 < 64; s4 += 4) {
      float4 b4 = *(const float4*)&xs[12 + n][s4];
      float4 c4 = *(const float4*)&xs[28 + n][s4];
      float4 p01 = *(const float4*)&dds[d_local][2 * s4];      // sp0,spu0,sp1,spu1
      float4 p23 = *(const float4*)&dds[d_local][2 * s4 + 4];  // sp2,spu2,sp3,spu3
      float4 u4 = *(const float4*)&us[d_local][s4];
      float e0 = exp2f(p01.x * A2);
      float e1 = exp2f(p01.z * A2);
      float e2 = exp2f(p23.x * A2);
      float e3 = exp2f(p23.z * A2);
      h = fmaf(h, e0, p01.y * b4.x);
      float y0 = h * c4.x;
      h = fmaf(h, e1, p01.w * b4.y);
      float y1 = h * c4.y;
      h = fmaf(h, e2, p23.y * b4.z);
      float y2 = h * c4.z;
      h = fmaf(h, e3, p23.w * b4.w);
      float y3 = h * c4.w;
      y0 = rowsum16(y0);
      y1 = rowsum16(y1);
      y2 = rowsum16(y2);
      y3 = rowsum16(y3);
      if (red_lane) {
        float* yb = ysp + (size_t)(t0 + s4) * 384;
        yb[0 * 384] = fmaf(u4.x, Dskip, y0);
        yb[1 * 384] = fmaf(u4.y, Dskip, y1);
        yb[2 * 384] = fmaf(u4.z, Dskip, y2);
        yb[3 * 384] = fmaf(u4.w, Dskip, y3);
      }
    }
    __syncthreads();
  }
}

// ---------------------------------------------------------------- merge+LN
__global__ __launch_bounds__(384) void k_merge(const float* __restrict__ ys,
                                               const float* __restrict__ z1T,
                                               const float* __restrict__ ln_w,
                                               const float* __restrict__ ln_b,
                                               float* __restrict__ yln) {
  const int b = blockIdx.x / L;
  const int l = blockIdx.x % L;
  const int d = threadIdx.x;
  const int hh = l / 48, ww = l % 48;
  const int j = ww * 48 + hh;
  const float* base = ys + (size_t)b * 4 * L * 384;
  float v = base[(size_t)(0 * L + l) * 384 + d] +
            base[(size_t)(1 * L + j) * 384 + d] +
            base[(size_t)(2 * L + (2303 - l)) * 384 + d] +
            base[(size_t)(3 * L + (2303 - j)) * 384 + d];
  float s1 = v, s2 = v * v;
#pragma unroll
  for (int off = 32; off; off >>= 1) {
    s1 += __shfl_xor(s1, off);
    s2 += __shfl_xor(s2, off);
  }
  __shared__ float ps1[6], ps2[6];
  const int wv = threadIdx.x >> 6;
  if ((threadIdx.x & 63) == 0) { ps1[wv] = s1; ps2[wv] = s2; }
  __syncthreads();
  float t1 = 0.f, t2 = 0.f;
#pragma unroll
  for (int i = 0; i < 6; ++i) { t1 += ps1[i]; t2 += ps2[i]; }
  const float mu = t1 * (1.0f / 384.0f);
  const float var = t2 * (1.0f / 384.0f) - mu * mu;
  const float rs = rsqrtf(var + 1e-5f);
  const float yv = (v - mu) * rs * ln_w[d] + ln_b[d];
  yln[((size_t)b * L + l) * 384 + d] = yv * z1T[((size_t)b * L + l) * 384 + d];
}

// ---------------------------------------------------------------- out_proj
__global__ __launch_bounds__(256) void k_outproj(const float* __restrict__ yln,
                                                 const float* __restrict__ W2,
                                                 float* __restrict__ out) {
  const int l0 = blockIdx.x * 64;
  const int c0 = blockIdx.y * 64;
  const int b = blockIdx.z;
  const int tid = threadIdx.x;
  const int tx = tid & 15, ty = tid >> 4;
  __shared__ __align__(16) float As[16][64];  // [kk][l]
  __shared__ __align__(16) float Bs[16][64];  // [kk][c]
  float acc[4][4] = {};
  const float* ybase = yln + (size_t)b * L * 384;
  for (int k0 = 0; k0 < 384; k0 += 16) {
    {
      const int mm = tid & 63, kq = tid >> 6;
      float4 a = *(const float4*)&ybase[(size_t)(l0 + mm) * 384 + k0 + kq * 4];
      As[kq * 4 + 0][mm] = a.x; As[kq * 4 + 1][mm] = a.y;
      As[kq * 4 + 2][mm] = a.z; As[kq * 4 + 3][mm] = a.w;
    }
    {
      const int nn = tid & 63, kq = tid >> 6;
      float4 w = *(const float4*)&W2[(size_t)(c0 + nn) * 384 + k0 + kq * 4];
      Bs[kq * 4 + 0][nn] = w.x; Bs[kq * 4 + 1][nn] = w.y;
      Bs[kq * 4 + 2][nn] = w.z; Bs[kq * 4 + 3][nn] = w.w;
    }
    __syncthreads();
#pragma unroll
    for (int kk = 0; kk < 16; ++kk) {
      float4 a4 = *(const float4*)&As[kk][tx * 4];  // l
      float4 b4 = *(const float4*)&Bs[kk][ty * 4];  // c
      float av[4] = {a4.x, a4.y, a4.z, a4.w};
      float bv[4] = {b4.x, b4.y, b4.z, b4.w};
#pragma unroll
      for (int i = 0; i < 4; ++i)
#pragma unroll
        for (int j = 0; j < 4; ++j) acc[i][j] = fmaf(bv[i], av[j], acc[i][j]);
    }
    __syncthreads();
  }
#pragma unroll
  for (int i = 0; i < 4; ++i) {
    float4 v = make_float4(acc[i][0], acc[i][1], acc[i][2], acc[i][3]);
    *(float4*)&out[((size_t)b * 192 + c0 + ty * 4 + i) * L + l0 + tx * 4] = v;
  }
}

// ---------------------------------------------------------------- launch
extern "C" void kernel_launch(void* const* d_in, const int* in_sizes, int n_in,
                              void* d_out, int out_size, void* d_ws, size_t ws_size,
                              hipStream_t stream) {
  const float* x = (const float*)d_in[0];
  const float* in_proj_w = (const float*)d_in[1];
  const float* conv_w = (const float*)d_in[2];
  const float* conv_b = (const float*)d_in[3];
  const float* x_proj_w = (const float*)d_in[4];
  const float* dt_w = (const float*)d_in[5];
  const float* dt_b = (const float*)d_in[6];
  const float* A_logs = (const float*)d_in[7];
  const float* Ds = (const float*)d_in[8];
  const float* ln_w = (const float*)d_in[9];
  const float* ln_b = (const float*)d_in[10];
  const float* out_proj_w = (const float*)d_in[11];
  float* out = (float*)d_out;
  float* ws = (float*)d_ws;

  const size_t SZ_BDL = (size_t)8 * 384 * L;  // 7,077,888
  float* xx = ws;                      // (B,384,L), later reused as yln
  float* z1T = xx + SZ_BDL;            // (B,L,384)
  float* xconv = z1T + SZ_BDL;         // (B,384,L) hw
  float* xconvT = xconv + SZ_BDL;      // (B,384,L) wh
  float* xdbl = xconvT + SZ_BDL;       // (B,4,48,L)
  float* ys = xdbl + (size_t)8 * 4 * 48 * L;  // (B,4,L,384)
  float* yln = xx;                     // alias (xx dead after conv)

  k_inproj<<<dim3(36, 12, 8), 256, 0, stream>>>(x, in_proj_w, xx, z1T);
  k_conv<<<dim3(3072), 256, 0, stream>>>(xx, conv_w, conv_b, xconv, xconvT);
  k_xdbl<<<dim3(36, 32), 256, 0, stream>>>(xconv, xconvT, x_proj_w, xdbl);
  k_scan<<<dim3(768), 256, 0, stream>>>(xconv, xconvT, xdbl, dt_w, dt_b,
                                        A_logs, Ds, ys);
  k_merge<<<dim3(8 * L), 384, 0, stream>>>(ys, z1T, ln_w, ln_b, yln);
  k_outproj<<<dim3(36, 3, 8), 256, 0, stream>>>(yln, out_proj_w, out);
}